// Round 1
// baseline (563.882 us; speedup 1.0000x reference)
//
#include <hip/hip_runtime.h>

#define N_NODES 50000
#define N_EDGES 800000
#define ETOT    (N_EDGES + N_NODES)   // edges + self loops
#define NEG_SLOPE 0.2f

// ---- order-preserving float <-> uint encode for atomicMax ----
__device__ __forceinline__ unsigned fenc(float f) {
    unsigned u = __float_as_uint(f);
    return (u & 0x80000000u) ? ~u : (u | 0x80000000u);
}
__device__ __forceinline__ float fdec(unsigned u) {
    return __uint_as_float((u & 0x80000000u) ? (u & 0x7FFFFFFFu) : ~u);
}
#define ENC_NEG_INF 0x007FFFFFu   // fenc(-inf)

__device__ __forceinline__ void edge_src_dst(const int* ei, int e, int& src, int& dst) {
    if (e < N_EDGES) { src = ei[e]; dst = ei[N_EDGES + e]; }
    else             { src = dst = e - N_EDGES; }
}

// ============ Layer 1: node transform (x@W1), alpha_s/alpha_d, init accums ============
// block 256 = 4 waves, one wave (64 lanes) per node; lane j owns h1[node, j]
__global__ void k_node1(const float* __restrict__ x, const float* __restrict__ W1,
                        const float* __restrict__ a_src1, const float* __restrict__ a_dst1,
                        float* __restrict__ h1, float* __restrict__ o1,
                        float* __restrict__ as1, float* __restrict__ ad1,
                        unsigned* __restrict__ m1, float* __restrict__ den1) {
    int node = blockIdx.x * 4 + (threadIdx.x >> 6);
    if (node >= N_NODES) return;
    int j = threadIdx.x & 63;
    int head = j >> 5;

    float h = 0.f;
#pragma unroll
    for (int k = 0; k < 6; ++k)
        h += x[node * 6 + k] * W1[k * 64 + j];

    h1[node * 64 + j] = h;
    o1[node * 64 + j] = 0.f;

    // a_src1/a_dst1 are (2,32) row-major -> flat index == j
    float s = h * a_src1[j];
    float d = h * a_dst1[j];
#pragma unroll
    for (int m = 1; m < 32; m <<= 1) {
        s += __shfl_xor(s, m);
        d += __shfl_xor(d, m);
    }
    if ((j & 31) == 0) {
        as1[node * 2 + head] = s;
        ad1[node * 2 + head] = d;
        m1[node * 2 + head] = ENC_NEG_INF;
        den1[node * 2 + head] = 0.f;
    }
}

// ============ Layer 1 edge passes ============
__global__ void k_edge_max1(const int* __restrict__ ei, const float* __restrict__ as1,
                            const float* __restrict__ ad1, unsigned* __restrict__ m1) {
    int e = blockIdx.x * blockDim.x + threadIdx.x;
    if (e >= ETOT) return;
    int src, dst; edge_src_dst(ei, e, src, dst);
#pragma unroll
    for (int h = 0; h < 2; ++h) {
        float v = as1[src * 2 + h] + ad1[dst * 2 + h];
        v = v > 0.f ? v : NEG_SLOPE * v;
        atomicMax(&m1[dst * 2 + h], fenc(v));
    }
}

__global__ void k_edge_sum1(const int* __restrict__ ei, const float* __restrict__ as1,
                            const float* __restrict__ ad1, const unsigned* __restrict__ m1,
                            float* __restrict__ ex1, float* __restrict__ den1) {
    int e = blockIdx.x * blockDim.x + threadIdx.x;
    if (e >= ETOT) return;
    int src, dst; edge_src_dst(ei, e, src, dst);
#pragma unroll
    for (int h = 0; h < 2; ++h) {
        float v = as1[src * 2 + h] + ad1[dst * 2 + h];
        v = v > 0.f ? v : NEG_SLOPE * v;
        float ex = __expf(v - fdec(m1[dst * 2 + h]));
        ex1[e * 2 + h] = ex;
        atomicAdd(&den1[dst * 2 + h], ex);
    }
}

// one edge per 64 lanes, 4 edges per 256-block; lane j handles feature j
__global__ void k_edge_agg1(const int* __restrict__ ei, const float* __restrict__ ex1,
                            const float* __restrict__ h1, float* __restrict__ o1) {
    int idx = blockIdx.x * blockDim.x + threadIdx.x;
    int e = idx >> 6;
    if (e >= ETOT) return;
    int j = idx & 63;
    int src, dst; edge_src_dst(ei, e, src, dst);
    float w = ex1[e * 2 + (j >> 5)];
    atomicAdd(&o1[dst * 64 + j], w * h1[src * 64 + j]);
}

// normalize + bias + relu (in place on o1)
__global__ void k_fin1(float* __restrict__ o1, const float* __restrict__ den1,
                       const float* __restrict__ b1) {
    int idx = blockIdx.x * blockDim.x + threadIdx.x;
    if (idx >= N_NODES * 64) return;
    int node = idx >> 6;
    int j = idx & 63;
    float v = o1[idx] / den1[node * 2 + (j >> 5)] + b1[j];
    o1[idx] = v > 0.f ? v : 0.f;
}

// ============ Layer 2: node transform (relu_out1 @ W2), alpha2, init ============
// block 256 = 8 subgroups of 32, one subgroup per node; W2 (64x32) staged in LDS
__global__ void k_node2(const float* __restrict__ o1, const float* __restrict__ W2,
                        const float* __restrict__ a_src2, const float* __restrict__ a_dst2,
                        float* __restrict__ h2, float* __restrict__ o2,
                        float* __restrict__ as2, float* __restrict__ ad2,
                        unsigned* __restrict__ m2, float* __restrict__ den2) {
    __shared__ float W2s[64 * 32];
    for (int i = threadIdx.x; i < 64 * 32; i += 256)
        W2s[i] = W2[i];
    __syncthreads();

    int node = blockIdx.x * 8 + (threadIdx.x >> 5);
    if (node >= N_NODES) return;
    int j = threadIdx.x & 31;

    float acc = 0.f;
#pragma unroll
    for (int k = 0; k < 64; ++k)
        acc += o1[node * 64 + k] * W2s[k * 32 + j];

    h2[node * 32 + j] = acc;
    o2[node * 32 + j] = 0.f;

    float s = acc * a_src2[j];
    float d = acc * a_dst2[j];
#pragma unroll
    for (int m = 1; m < 32; m <<= 1) {
        s += __shfl_xor(s, m);
        d += __shfl_xor(d, m);
    }
    if (j == 0) {
        as2[node] = s;
        ad2[node] = d;
        m2[node] = ENC_NEG_INF;
        den2[node] = 0.f;
    }
}

// ============ Layer 2 edge passes (H=1) ============
__global__ void k_edge_max2(const int* __restrict__ ei, const float* __restrict__ as2,
                            const float* __restrict__ ad2, unsigned* __restrict__ m2) {
    int e = blockIdx.x * blockDim.x + threadIdx.x;
    if (e >= ETOT) return;
    int src, dst; edge_src_dst(ei, e, src, dst);
    float v = as2[src] + ad2[dst];
    v = v > 0.f ? v : NEG_SLOPE * v;
    atomicMax(&m2[dst], fenc(v));
}

__global__ void k_edge_sum2(const int* __restrict__ ei, const float* __restrict__ as2,
                            const float* __restrict__ ad2, const unsigned* __restrict__ m2,
                            float* __restrict__ ex2, float* __restrict__ den2) {
    int e = blockIdx.x * blockDim.x + threadIdx.x;
    if (e >= ETOT) return;
    int src, dst; edge_src_dst(ei, e, src, dst);
    float v = as2[src] + ad2[dst];
    v = v > 0.f ? v : NEG_SLOPE * v;
    float ex = __expf(v - fdec(m2[dst]));
    ex2[e] = ex;
    atomicAdd(&den2[dst], ex);
}

// one edge per 32 lanes, 8 edges per 256-block
__global__ void k_edge_agg2(const int* __restrict__ ei, const float* __restrict__ ex2,
                            const float* __restrict__ h2, float* __restrict__ o2) {
    int idx = blockIdx.x * blockDim.x + threadIdx.x;
    int e = idx >> 5;
    if (e >= ETOT) return;
    int j = idx & 31;
    int src, dst; edge_src_dst(ei, e, src, dst);
    float w = ex2[e];
    atomicAdd(&o2[dst * 32 + j], w * h2[src * 32 + j]);
}

// normalize + bias + relu + (h @ Wout + bout) + sigmoid
__global__ void k_fin2(const float* __restrict__ o2, const float* __restrict__ den2,
                       const float* __restrict__ b2, const float* __restrict__ Wout,
                       const float* __restrict__ bout, float* __restrict__ out) {
    int node = blockIdx.x * 8 + (threadIdx.x >> 5);
    if (node >= N_NODES) return;
    int j = threadIdx.x & 31;
    float v = o2[node * 32 + j] / den2[node] + b2[j];
    v = v > 0.f ? v : 0.f;
    float t = v * Wout[j];
#pragma unroll
    for (int m = 1; m < 32; m <<= 1)
        t += __shfl_xor(t, m);
    if (j == 0)
        out[node] = 1.f / (1.f + __expf(-(t + bout[0])));
}

extern "C" void kernel_launch(void* const* d_in, const int* in_sizes, int n_in,
                              void* d_out, int out_size, void* d_ws, size_t ws_size,
                              hipStream_t stream) {
    const float* x     = (const float*)d_in[0];
    const int*   ei    = (const int*)  d_in[1];
    const float* W1    = (const float*)d_in[2];
    const float* asw1  = (const float*)d_in[3];
    const float* adw1  = (const float*)d_in[4];
    const float* b1    = (const float*)d_in[5];
    const float* W2    = (const float*)d_in[6];
    const float* asw2  = (const float*)d_in[7];
    const float* adw2  = (const float*)d_in[8];
    const float* b2    = (const float*)d_in[9];
    const float* Wout  = (const float*)d_in[10];
    const float* bout  = (const float*)d_in[11];
    float* out = (float*)d_out;

    char* p = (char*)d_ws;
    auto carve = [&](size_t bytes) {
        void* r = (void*)p;
        p += (bytes + 255) & ~size_t(255);
        return r;
    };
    float*    h1   = (float*)   carve((size_t)N_NODES * 64 * 4);
    float*    o1   = (float*)   carve((size_t)N_NODES * 64 * 4);
    float*    as1  = (float*)   carve((size_t)N_NODES * 2 * 4);
    float*    ad1  = (float*)   carve((size_t)N_NODES * 2 * 4);
    unsigned* m1   = (unsigned*)carve((size_t)N_NODES * 2 * 4);
    float*    den1 = (float*)   carve((size_t)N_NODES * 2 * 4);
    float*    ex1  = (float*)   carve((size_t)ETOT * 2 * 4);
    float*    h2   = (float*)   carve((size_t)N_NODES * 32 * 4);
    float*    o2   = (float*)   carve((size_t)N_NODES * 32 * 4);
    float*    as2  = (float*)   carve((size_t)N_NODES * 4);
    float*    ad2  = (float*)   carve((size_t)N_NODES * 4);
    unsigned* m2   = (unsigned*)carve((size_t)N_NODES * 4);
    float*    den2 = (float*)   carve((size_t)N_NODES * 4);
    float*    ex2  = (float*)   carve((size_t)ETOT * 4);

    const int TB = 256;
    int g_edge_t  = (ETOT + TB - 1) / TB;        // thread per edge
    int g_agg1    = (ETOT * 64 + TB - 1) / TB;   // 64 lanes per edge
    int g_agg2    = (ETOT * 32 + TB - 1) / TB;   // 32 lanes per edge

    // ---- layer 1 ----
    k_node1<<<(N_NODES + 3) / 4, TB, 0, stream>>>(x, W1, asw1, adw1, h1, o1, as1, ad1, m1, den1);
    k_edge_max1<<<g_edge_t, TB, 0, stream>>>(ei, as1, ad1, m1);
    k_edge_sum1<<<g_edge_t, TB, 0, stream>>>(ei, as1, ad1, m1, ex1, den1);
    k_edge_agg1<<<g_agg1, TB, 0, stream>>>(ei, ex1, h1, o1);
    k_fin1<<<(N_NODES * 64 + TB - 1) / TB, TB, 0, stream>>>(o1, den1, b1);

    // ---- layer 2 ----
    k_node2<<<(N_NODES + 7) / 8, TB, 0, stream>>>(o1, W2, asw2, adw2, h2, o2, as2, ad2, m2, den2);
    k_edge_max2<<<g_edge_t, TB, 0, stream>>>(ei, as2, ad2, m2);
    k_edge_sum2<<<g_edge_t, TB, 0, stream>>>(ei, as2, ad2, m2, ex2, den2);
    k_edge_agg2<<<g_agg2, TB, 0, stream>>>(ei, ex2, h2, o2);
    k_fin2<<<(N_NODES + 7) / 8, TB, 0, stream>>>(o2, den2, b2, Wout, bout, out);
}

// Round 2
// 221.867 us; speedup vs baseline: 2.5415x; 2.5415x over previous
//
#include <hip/hip_runtime.h>

#define N_NODES 50000
#define N_EDGES 800000
#define ETOT    (N_EDGES + N_NODES)   // edges + self loops
#define NEG_SLOPE 0.2f
#define NBLK_SCAN ((N_NODES + 255) / 256)

__device__ __forceinline__ float leaky(float v) {
    return v > 0.f ? v : NEG_SLOPE * v;
}

__device__ __forceinline__ void edge_src_dst(const int* ei, int e, int& src, int& dst) {
    if (e < N_EDGES) { src = ei[e]; dst = ei[N_EDGES + e]; }
    else             { src = dst = e - N_EDGES; }
}

// ================= CSR build =================
__global__ void k_zero(int* __restrict__ deg) {
    int i = blockIdx.x * blockDim.x + threadIdx.x;
    if (i < N_NODES) deg[i] = 0;
}

__global__ void k_hist(const int* __restrict__ ei, int* __restrict__ deg) {
    int e = blockIdx.x * blockDim.x + threadIdx.x;
    if (e >= ETOT) return;
    int src, dst; edge_src_dst(ei, e, src, dst);
    atomicAdd(&deg[dst], 1);
}

// per-256-block exclusive scan; emits per-block total
__global__ void k_scan_a(const int* __restrict__ deg, int* __restrict__ partial,
                         int* __restrict__ blocksum) {
    __shared__ int s[256];
    int i = blockIdx.x * 256 + threadIdx.x;
    int v = (i < N_NODES) ? deg[i] : 0;
    int x = v;
    s[threadIdx.x] = x;
    __syncthreads();
#pragma unroll
    for (int o = 1; o < 256; o <<= 1) {
        int t = (threadIdx.x >= o) ? s[threadIdx.x - o] : 0;
        __syncthreads();
        x += t;
        s[threadIdx.x] = x;
        __syncthreads();
    }
    if (i < N_NODES) partial[i] = x - v;          // exclusive within block
    if (threadIdx.x == 255) blocksum[blockIdx.x] = x;
}

// single-block exclusive scan of the block sums (NBLK_SCAN <= 256)
__global__ void k_scan_b(const int* __restrict__ blocksum, int* __restrict__ blockoff) {
    __shared__ int s[256];
    int i = threadIdx.x;
    int v = (i < NBLK_SCAN) ? blocksum[i] : 0;
    int x = v;
    s[i] = x;
    __syncthreads();
#pragma unroll
    for (int o = 1; o < 256; o <<= 1) {
        int t = (i >= o) ? s[i - o] : 0;
        __syncthreads();
        x += t;
        s[i] = x;
        __syncthreads();
    }
    if (i < NBLK_SCAN) blockoff[i] = x - v;
}

__global__ void k_scan_c(const int* __restrict__ partial, const int* __restrict__ blockoff,
                         int* __restrict__ rowstart, int* __restrict__ cursor) {
    int i = blockIdx.x * blockDim.x + threadIdx.x;
    if (i >= N_NODES) return;
    int r = partial[i] + blockoff[i >> 8];
    rowstart[i] = r;
    cursor[i] = r;
    if (i == 0) rowstart[N_NODES] = ETOT;
}

__global__ void k_scatter(const int* __restrict__ ei, int* __restrict__ cursor,
                          int* __restrict__ csr_src) {
    int e = blockIdx.x * blockDim.x + threadIdx.x;
    if (e >= ETOT) return;
    int src, dst; edge_src_dst(ei, e, src, dst);
    int pos = atomicAdd(&cursor[dst], 1);
    csr_src[pos] = src;
}

// ============ Layer 1 node transform: h1 = x@W1, alpha logits ============
// one wave per node; lane j owns h1[node, j]
__global__ void k_node1(const float* __restrict__ x, const float* __restrict__ W1,
                        const float* __restrict__ a_src1, const float* __restrict__ a_dst1,
                        float* __restrict__ h1, float* __restrict__ as1,
                        float* __restrict__ ad1) {
    int node = blockIdx.x * 4 + (threadIdx.x >> 6);
    if (node >= N_NODES) return;
    int j = threadIdx.x & 63;
    int head = j >> 5;

    float h = 0.f;
#pragma unroll
    for (int k = 0; k < 6; ++k)
        h += x[node * 6 + k] * W1[k * 64 + j];
    h1[node * 64 + j] = h;

    float s = h * a_src1[j];   // a_src1 (2,32) flat == j
    float d = h * a_dst1[j];
#pragma unroll
    for (int m = 1; m < 32; m <<= 1) {
        s += __shfl_xor(s, m);
        d += __shfl_xor(d, m);
    }
    if ((j & 31) == 0) {
        as1[node * 2 + head] = s;
        ad1[node * 2 + head] = d;
    }
}

// ============ Layer 1 fused softmax + aggregate: one wave per dst node ============
__global__ void k_gat1(const int* __restrict__ csr_src, const int* __restrict__ rowstart,
                       const float* __restrict__ as1, const float* __restrict__ ad1,
                       const float* __restrict__ h1, const float* __restrict__ b1,
                       float* __restrict__ o1) {
    int node = blockIdx.x * 4 + (threadIdx.x >> 6);
    if (node >= N_NODES) return;
    int j = threadIdx.x & 63;
    int head = j >> 5;
    int beg = rowstart[node], end = rowstart[node + 1];
    float adv0 = ad1[node * 2 + 0];
    float adv1 = ad1[node * 2 + 1];

    // pass A: max over incoming edges (both heads), lane-parallel
    float m0 = -1e30f, m1 = -1e30f;
    for (int base = beg; base < end; base += 64) {
        int idx = base + j;
        if (idx < end) {
            int s = csr_src[idx];
            m0 = fmaxf(m0, leaky(as1[s * 2 + 0] + adv0));
            m1 = fmaxf(m1, leaky(as1[s * 2 + 1] + adv1));
        }
    }
#pragma unroll
    for (int o = 32; o; o >>= 1) {
        m0 = fmaxf(m0, __shfl_xor(m0, o));
        m1 = fmaxf(m1, __shfl_xor(m1, o));
    }

    // pass B: exp weights + weighted feature gather
    float acc = 0.f, dp0 = 0.f, dp1 = 0.f;
    for (int base = beg; base < end; base += 64) {
        int idx = base + j;
        int cnt = min(64, end - base);
        float w0 = 0.f, w1 = 0.f;
        int s = 0;
        if (idx < end) {
            s = csr_src[idx];
            w0 = __expf(leaky(as1[s * 2 + 0] + adv0) - m0);
            w1 = __expf(leaky(as1[s * 2 + 1] + adv1) - m1);
            dp0 += w0;
            dp1 += w1;
        }
        int k = 0;
        for (; k + 16 <= cnt; k += 16) {
#pragma unroll
            for (int u = 0; u < 16; ++u) {
                int   sk  = __shfl(s,  k + u);
                float w0k = __shfl(w0, k + u);
                float w1k = __shfl(w1, k + u);
                acc += (head ? w1k : w0k) * h1[sk * 64 + j];
            }
        }
        for (; k < cnt; ++k) {
            int   sk  = __shfl(s,  k);
            float w0k = __shfl(w0, k);
            float w1k = __shfl(w1, k);
            acc += (head ? w1k : w0k) * h1[sk * 64 + j];
        }
    }
#pragma unroll
    for (int o = 32; o; o >>= 1) {
        dp0 += __shfl_xor(dp0, o);
        dp1 += __shfl_xor(dp1, o);
    }
    float den = head ? dp1 : dp0;
    float v = acc / den + b1[j];
    o1[node * 64 + j] = v > 0.f ? v : 0.f;    // bias + relu fused
}

// ============ Layer 2 node transform: h2 = o1@W2, alpha logits ============
__global__ void k_node2(const float* __restrict__ o1, const float* __restrict__ W2,
                        const float* __restrict__ a_src2, const float* __restrict__ a_dst2,
                        float* __restrict__ h2, float* __restrict__ as2,
                        float* __restrict__ ad2) {
    __shared__ float W2s[64 * 32];
    for (int i = threadIdx.x; i < 64 * 32; i += 256)
        W2s[i] = W2[i];
    __syncthreads();

    int node = blockIdx.x * 8 + (threadIdx.x >> 5);
    if (node >= N_NODES) return;
    int j = threadIdx.x & 31;

    float acc = 0.f;
#pragma unroll
    for (int k = 0; k < 64; ++k)
        acc += o1[node * 64 + k] * W2s[k * 32 + j];
    h2[node * 32 + j] = acc;

    float s = acc * a_src2[j];
    float d = acc * a_dst2[j];
#pragma unroll
    for (int m = 1; m < 32; m <<= 1) {
        s += __shfl_xor(s, m, 32);
        d += __shfl_xor(d, m, 32);
    }
    if (j == 0) {
        as2[node] = s;
        ad2[node] = d;
    }
}

// ============ Layer 2 fused softmax + aggregate + output head ============
// one 32-lane group per dst node (8 per block)
__global__ void k_gat2(const int* __restrict__ csr_src, const int* __restrict__ rowstart,
                       const float* __restrict__ as2, const float* __restrict__ ad2,
                       const float* __restrict__ h2, const float* __restrict__ b2,
                       const float* __restrict__ Wout, const float* __restrict__ bout,
                       float* __restrict__ out) {
    int node = blockIdx.x * 8 + (threadIdx.x >> 5);
    if (node >= N_NODES) return;
    int j = threadIdx.x & 31;
    int beg = rowstart[node], end = rowstart[node + 1];
    float adv = ad2[node];

    float m = -1e30f;
    for (int base = beg; base < end; base += 32) {
        int idx = base + j;
        if (idx < end)
            m = fmaxf(m, leaky(as2[csr_src[idx]] + adv));
    }
#pragma unroll
    for (int o = 16; o; o >>= 1)
        m = fmaxf(m, __shfl_xor(m, o, 32));

    float acc = 0.f, dp = 0.f;
    for (int base = beg; base < end; base += 32) {
        int idx = base + j;
        int cnt = min(32, end - base);
        float w = 0.f;
        int s = 0;
        if (idx < end) {
            s = csr_src[idx];
            w = __expf(leaky(as2[s] + adv) - m);
            dp += w;
        }
        int k = 0;
        for (; k + 16 <= cnt; k += 16) {
#pragma unroll
            for (int u = 0; u < 16; ++u) {
                int   sk = __shfl(s, k + u, 32);
                float wk = __shfl(w, k + u, 32);
                acc += wk * h2[sk * 32 + j];
            }
        }
        for (; k < cnt; ++k) {
            int   sk = __shfl(s, k, 32);
            float wk = __shfl(w, k, 32);
            acc += wk * h2[sk * 32 + j];
        }
    }
#pragma unroll
    for (int o = 16; o; o >>= 1)
        dp += __shfl_xor(dp, o, 32);

    float v = acc / dp + b2[j];
    v = v > 0.f ? v : 0.f;                 // relu
    float t = v * Wout[j];                 // output head
#pragma unroll
    for (int o = 16; o; o >>= 1)
        t += __shfl_xor(t, o, 32);
    if (j == 0)
        out[node] = 1.f / (1.f + __expf(-(t + bout[0])));
}

extern "C" void kernel_launch(void* const* d_in, const int* in_sizes, int n_in,
                              void* d_out, int out_size, void* d_ws, size_t ws_size,
                              hipStream_t stream) {
    const float* x    = (const float*)d_in[0];
    const int*   ei   = (const int*)  d_in[1];
    const float* W1   = (const float*)d_in[2];
    const float* asw1 = (const float*)d_in[3];
    const float* adw1 = (const float*)d_in[4];
    const float* b1   = (const float*)d_in[5];
    const float* W2   = (const float*)d_in[6];
    const float* asw2 = (const float*)d_in[7];
    const float* adw2 = (const float*)d_in[8];
    const float* b2   = (const float*)d_in[9];
    const float* Wout = (const float*)d_in[10];
    const float* bout = (const float*)d_in[11];
    float* out = (float*)d_out;

    char* p = (char*)d_ws;
    auto carve = [&](size_t bytes) {
        void* r = (void*)p;
        p += (bytes + 255) & ~size_t(255);
        return r;
    };
    float* h1       = (float*)carve((size_t)N_NODES * 64 * 4);
    float* o1       = (float*)carve((size_t)N_NODES * 64 * 4);
    float* h2       = (float*)carve((size_t)N_NODES * 32 * 4);
    float* as1      = (float*)carve((size_t)N_NODES * 2 * 4);
    float* ad1      = (float*)carve((size_t)N_NODES * 2 * 4);
    float* as2      = (float*)carve((size_t)N_NODES * 4);
    float* ad2      = (float*)carve((size_t)N_NODES * 4);
    int*   deg      = (int*)  carve((size_t)N_NODES * 4);
    int*   partial  = (int*)  carve((size_t)N_NODES * 4);
    int*   blocksum = (int*)  carve(256 * 4);
    int*   blockoff = (int*)  carve(256 * 4);
    int*   rowstart = (int*)  carve((size_t)(N_NODES + 1) * 4);
    int*   cursor   = (int*)  carve((size_t)N_NODES * 4);
    int*   csr_src  = (int*)  carve((size_t)ETOT * 4);

    const int TB = 256;
    int g_node   = (N_NODES + TB - 1) / TB;
    int g_edge   = (ETOT + TB - 1) / TB;

    // ---- CSR build (shared by both layers) ----
    k_zero   <<<g_node, TB, 0, stream>>>(deg);
    k_hist   <<<g_edge, TB, 0, stream>>>(ei, deg);
    k_scan_a <<<NBLK_SCAN, TB, 0, stream>>>(deg, partial, blocksum);
    k_scan_b <<<1, TB, 0, stream>>>(blocksum, blockoff);
    k_scan_c <<<g_node, TB, 0, stream>>>(partial, blockoff, rowstart, cursor);
    k_scatter<<<g_edge, TB, 0, stream>>>(ei, cursor, csr_src);

    // ---- layer 1 ----
    k_node1<<<(N_NODES + 3) / 4, TB, 0, stream>>>(x, W1, asw1, adw1, h1, as1, ad1);
    k_gat1 <<<(N_NODES + 3) / 4, TB, 0, stream>>>(csr_src, rowstart, as1, ad1, h1, b1, o1);

    // ---- layer 2 ----
    k_node2<<<(N_NODES + 7) / 8, TB, 0, stream>>>(o1, W2, asw2, adw2, h2, as2, ad2);
    k_gat2 <<<(N_NODES + 7) / 8, TB, 0, stream>>>(csr_src, rowstart, as2, ad2, h2, b2, Wout, bout, out);
}

// Round 3
// 199.164 us; speedup vs baseline: 2.8312x; 1.1140x over previous
//
#include <hip/hip_runtime.h>

#define N_NODES 50000
#define N_EDGES 800000
#define ETOT    (N_EDGES + N_NODES)   // edges + self loops
#define NEG_SLOPE 0.2f
#define NBLK_SCAN ((N_NODES + 255) / 256)

__device__ __forceinline__ float leaky(float v) {
    return v > 0.f ? v : NEG_SLOPE * v;
}

__device__ __forceinline__ float rl_f(float v, int lane) {
    return __uint_as_float(__builtin_amdgcn_readlane(__float_as_uint(v), lane));
}
__device__ __forceinline__ int rl_i(int v, int lane) {
    return __builtin_amdgcn_readlane(v, lane);
}

__device__ __forceinline__ void edge_src_dst(const int* ei, int e, int& src, int& dst) {
    if (e < N_EDGES) { src = ei[e]; dst = ei[N_EDGES + e]; }
    else             { src = dst = e - N_EDGES; }
}

// ================= CSR build =================
__global__ void k_zero(int* __restrict__ deg) {
    int i = blockIdx.x * blockDim.x + threadIdx.x;
    if (i < N_NODES) deg[i] = 0;
}

__global__ void k_hist(const int* __restrict__ ei, int* __restrict__ deg) {
    int e = blockIdx.x * blockDim.x + threadIdx.x;
    if (e >= ETOT) return;
    int src, dst; edge_src_dst(ei, e, src, dst);
    atomicAdd(&deg[dst], 1);
}

__global__ void k_scan_a(const int* __restrict__ deg, int* __restrict__ partial,
                         int* __restrict__ blocksum) {
    __shared__ int s[256];
    int i = blockIdx.x * 256 + threadIdx.x;
    int v = (i < N_NODES) ? deg[i] : 0;
    int x = v;
    s[threadIdx.x] = x;
    __syncthreads();
#pragma unroll
    for (int o = 1; o < 256; o <<= 1) {
        int t = (threadIdx.x >= o) ? s[threadIdx.x - o] : 0;
        __syncthreads();
        x += t;
        s[threadIdx.x] = x;
        __syncthreads();
    }
    if (i < N_NODES) partial[i] = x - v;
    if (threadIdx.x == 255) blocksum[blockIdx.x] = x;
}

__global__ void k_scan_b(const int* __restrict__ blocksum, int* __restrict__ blockoff) {
    __shared__ int s[256];
    int i = threadIdx.x;
    int v = (i < NBLK_SCAN) ? blocksum[i] : 0;
    int x = v;
    s[i] = x;
    __syncthreads();
#pragma unroll
    for (int o = 1; o < 256; o <<= 1) {
        int t = (i >= o) ? s[i - o] : 0;
        __syncthreads();
        x += t;
        s[i] = x;
        __syncthreads();
    }
    if (i < NBLK_SCAN) blockoff[i] = x - v;
}

__global__ void k_scan_c(const int* __restrict__ partial, const int* __restrict__ blockoff,
                         int* __restrict__ rowstart, int* __restrict__ cursor) {
    int i = blockIdx.x * blockDim.x + threadIdx.x;
    if (i >= N_NODES) return;
    int r = partial[i] + blockoff[i >> 8];
    rowstart[i] = r;
    cursor[i] = r;
    if (i == 0) rowstart[N_NODES] = ETOT;
}

__global__ void k_scatter(const int* __restrict__ ei, int* __restrict__ cursor,
                          int* __restrict__ csr_src) {
    int e = blockIdx.x * blockDim.x + threadIdx.x;
    if (e >= ETOT) return;
    int src, dst; edge_src_dst(ei, e, src, dst);
    int pos = atomicAdd(&cursor[dst], 1);
    csr_src[pos] = src;
}

// ============ Layer 1 node transform: h1 = x@W1, alpha logits ============
__global__ void k_node1(const float* __restrict__ x, const float* __restrict__ W1,
                        const float* __restrict__ a_src1, const float* __restrict__ a_dst1,
                        float* __restrict__ h1, float* __restrict__ as1,
                        float* __restrict__ ad1) {
    int node = blockIdx.x * 4 + (threadIdx.x >> 6);
    if (node >= N_NODES) return;
    int j = threadIdx.x & 63;
    int head = j >> 5;

    float h = 0.f;
#pragma unroll
    for (int k = 0; k < 6; ++k)
        h += x[node * 6 + k] * W1[k * 64 + j];
    h1[node * 64 + j] = h;

    float s = h * a_src1[j];
    float d = h * a_dst1[j];
#pragma unroll
    for (int m = 1; m < 32; m <<= 1) {
        s += __shfl_xor(s, m);
        d += __shfl_xor(d, m);
    }
    if ((j & 31) == 0) {
        as1[node * 2 + head] = s;   // interleaved (node,head) -> float2-gatherable
        ad1[node * 2 + head] = d;
    }
}

// ============ Layer 1 fused softmax(no-max) + aggregate: one wave per dst ============
__global__ void k_gat1(const int* __restrict__ csr_src, const int* __restrict__ rowstart,
                       const float* __restrict__ as1, const float* __restrict__ ad1,
                       const float* __restrict__ h1, const float* __restrict__ b1,
                       float* __restrict__ o1) {
    int node = blockIdx.x * 4 + (threadIdx.x >> 6);
    if (node >= N_NODES) return;
    int j = threadIdx.x & 63;
    int head = j >> 5;
    int beg = rowstart[node], end = rowstart[node + 1];
    float adv0 = ad1[node * 2 + 0];
    float adv1 = ad1[node * 2 + 1];

    float acc = 0.f, dp0 = 0.f, dp1 = 0.f;
    for (int base = beg; base < end; base += 64) {
        int idx = base + j;
        int cnt = min(64, end - base);
        float w0 = 0.f, w1 = 0.f;
        int s = 0;
        if (idx < end) {
            s = csr_src[idx];
            float2 a = ((const float2*)as1)[s];
            w0 = __expf(leaky(a.x + adv0));   // no max subtraction: logits are O(1)
            w1 = __expf(leaky(a.y + adv1));
            dp0 += w0;
            dp1 += w1;
        }
        int k = 0;
        for (; k + 16 <= cnt; k += 16) {
#pragma unroll
            for (int u = 0; u < 16; ++u) {
                int   sk  = rl_i(s,  k + u);     // uniform index -> v_readlane (no LDS)
                float w0k = rl_f(w0, k + u);
                float w1k = rl_f(w1, k + u);
                acc += (head ? w1k : w0k) * h1[sk * 64 + j];
            }
        }
        for (; k < cnt; ++k) {
            int   sk  = rl_i(s,  k);
            float w0k = rl_f(w0, k);
            float w1k = rl_f(w1, k);
            acc += (head ? w1k : w0k) * h1[sk * 64 + j];
        }
    }
#pragma unroll
    for (int o = 32; o; o >>= 1) {
        dp0 += __shfl_xor(dp0, o);
        dp1 += __shfl_xor(dp1, o);
    }
    float den = head ? dp1 : dp0;
    float v = acc / den + b1[j];
    o1[node * 64 + j] = v > 0.f ? v : 0.f;    // bias + relu fused
}

// ============ Layer 2 node transform: h2 = o1@W2, alpha logits ============
__global__ void k_node2(const float* __restrict__ o1, const float* __restrict__ W2,
                        const float* __restrict__ a_src2, const float* __restrict__ a_dst2,
                        float* __restrict__ h2, float* __restrict__ as2,
                        float* __restrict__ ad2) {
    __shared__ float W2s[64 * 32];
    for (int i = threadIdx.x; i < 64 * 32; i += 256)
        W2s[i] = W2[i];
    __syncthreads();

    int node = blockIdx.x * 8 + (threadIdx.x >> 5);
    if (node >= N_NODES) return;
    int j = threadIdx.x & 31;

    float acc = 0.f;
#pragma unroll
    for (int k = 0; k < 64; ++k)
        acc += o1[node * 64 + k] * W2s[k * 32 + j];
    h2[node * 32 + j] = acc;

    float s = acc * a_src2[j];
    float d = acc * a_dst2[j];
#pragma unroll
    for (int m = 1; m < 32; m <<= 1) {
        s += __shfl_xor(s, m, 32);
        d += __shfl_xor(d, m, 32);
    }
    if (j == 0) {
        as2[node] = s;
        ad2[node] = d;
    }
}

// ============ Layer 2 fused softmax(no-max) + aggregate + output head ============
// one full wave per node: lane = (edge-slot parity)<<5 | feature
__global__ void k_gat2(const int* __restrict__ csr_src, const int* __restrict__ rowstart,
                       const float* __restrict__ as2, const float* __restrict__ ad2,
                       const float* __restrict__ h2, const float* __restrict__ b2,
                       const float* __restrict__ Wout, const float* __restrict__ bout,
                       float* __restrict__ out) {
    int node = blockIdx.x * 4 + (threadIdx.x >> 6);
    if (node >= N_NODES) return;
    int j = threadIdx.x & 63;
    int f = j & 31;
    int half = j >> 5;
    int beg = rowstart[node], end = rowstart[node + 1];
    float adv = ad2[node];

    float acc = 0.f, dp = 0.f;
    for (int base = beg; base < end; base += 64) {
        int idx = base + j;
        int cnt = min(64, end - base);
        float w = 0.f;
        int s = 0;
        if (idx < end) {
            s = csr_src[idx];
            w = __expf(leaky(as2[s] + adv));
            dp += w;
        }
        int k = 0;
        for (; k + 8 <= cnt; k += 8) {
#pragma unroll
            for (int u = 0; u < 4; ++u) {      // 2 edges per step
                int   sa = rl_i(s, k + 2 * u);
                int   sb = rl_i(s, k + 2 * u + 1);
                float wa = rl_f(w, k + 2 * u);
                float wb = rl_f(w, k + 2 * u + 1);
                int   sk = half ? sb : sa;
                float wk = half ? wb : wa;
                acc += wk * h2[sk * 32 + f];
            }
        }
        for (; k + 2 <= cnt; k += 2) {
            int   sa = rl_i(s, k);
            int   sb = rl_i(s, k + 1);
            float wa = rl_f(w, k);
            float wb = rl_f(w, k + 1);
            int   sk = half ? sb : sa;
            float wk = half ? wb : wa;
            acc += wk * h2[sk * 32 + f];
        }
        if (k < cnt) {                          // odd tail edge
            int   sa = rl_i(s, k);
            float wa = rl_f(w, k);
            if (half == 0) acc += wa * h2[sa * 32 + f];
        }
    }
    // dp: each lane saw distinct edges -> full 64-lane sum
#pragma unroll
    for (int o = 32; o; o >>= 1)
        dp += __shfl_xor(dp, o);
    // acc: fold the two edge-slot halves; lanes j and j+32 then hold same value
    acc += __shfl_xor(acc, 32);

    float v = acc / dp + b2[f];
    v = v > 0.f ? v : 0.f;
    float t = v * Wout[f];
#pragma unroll
    for (int o = 16; o; o >>= 1)
        t += __shfl_xor(t, o);
    if (j == 0)
        out[node] = 1.f / (1.f + __expf(-(t + bout[0])));
}

extern "C" void kernel_launch(void* const* d_in, const int* in_sizes, int n_in,
                              void* d_out, int out_size, void* d_ws, size_t ws_size,
                              hipStream_t stream) {
    const float* x    = (const float*)d_in[0];
    const int*   ei   = (const int*)  d_in[1];
    const float* W1   = (const float*)d_in[2];
    const float* asw1 = (const float*)d_in[3];
    const float* adw1 = (const float*)d_in[4];
    const float* b1   = (const float*)d_in[5];
    const float* W2   = (const float*)d_in[6];
    const float* asw2 = (const float*)d_in[7];
    const float* adw2 = (const float*)d_in[8];
    const float* b2   = (const float*)d_in[9];
    const float* Wout = (const float*)d_in[10];
    const float* bout = (const float*)d_in[11];
    float* out = (float*)d_out;

    char* p = (char*)d_ws;
    auto carve = [&](size_t bytes) {
        void* r = (void*)p;
        p += (bytes + 255) & ~size_t(255);
        return r;
    };
    float* h1       = (float*)carve((size_t)N_NODES * 64 * 4);
    float* o1       = (float*)carve((size_t)N_NODES * 64 * 4);
    float* h2       = (float*)carve((size_t)N_NODES * 32 * 4);
    float* as1      = (float*)carve((size_t)N_NODES * 2 * 4);
    float* ad1      = (float*)carve((size_t)N_NODES * 2 * 4);
    float* as2      = (float*)carve((size_t)N_NODES * 4);
    float* ad2      = (float*)carve((size_t)N_NODES * 4);
    int*   deg      = (int*)  carve((size_t)N_NODES * 4);
    int*   partial  = (int*)  carve((size_t)N_NODES * 4);
    int*   blocksum = (int*)  carve(256 * 4);
    int*   blockoff = (int*)  carve(256 * 4);
    int*   rowstart = (int*)  carve((size_t)(N_NODES + 1) * 4);
    int*   cursor   = (int*)  carve((size_t)N_NODES * 4);
    int*   csr_src  = (int*)  carve((size_t)ETOT * 4);

    const int TB = 256;
    int g_node = (N_NODES + TB - 1) / TB;
    int g_edge = (ETOT + TB - 1) / TB;

    // ---- CSR build ----
    k_zero   <<<g_node, TB, 0, stream>>>(deg);
    k_hist   <<<g_edge, TB, 0, stream>>>(ei, deg);
    k_scan_a <<<NBLK_SCAN, TB, 0, stream>>>(deg, partial, blocksum);
    k_scan_b <<<1, TB, 0, stream>>>(blocksum, blockoff);
    k_scan_c <<<g_node, TB, 0, stream>>>(partial, blockoff, rowstart, cursor);
    k_scatter<<<g_edge, TB, 0, stream>>>(ei, cursor, csr_src);

    // ---- layer 1 ----
    k_node1<<<(N_NODES + 3) / 4, TB, 0, stream>>>(x, W1, asw1, adw1, h1, as1, ad1);
    k_gat1 <<<(N_NODES + 3) / 4, TB, 0, stream>>>(csr_src, rowstart, as1, ad1, h1, b1, o1);

    // ---- layer 2 ----
    k_node2<<<(N_NODES + 7) / 8, TB, 0, stream>>>(o1, W2, asw2, adw2, h2, as2, ad2);
    k_gat2 <<<(N_NODES + 3) / 4, TB, 0, stream>>>(csr_src, rowstart, as2, ad2, h2, b2, Wout, bout, out);
}

// Round 4
// 147.102 us; speedup vs baseline: 3.8333x; 1.3539x over previous
//
#include <hip/hip_runtime.h>

#define N_NODES 50000
#define N_EDGES 800000
#define ETOT    (N_EDGES + N_NODES)   // edges + self loops
#define NEG_SLOPE 0.2f
#define NBIN    ((N_NODES + 255) / 256)     // 196 coarse bins (dst>>8)
#define CHUNK   4096
#define B_COARSE ((ETOT + CHUNK - 1) / CHUNK)  // 208 blocks

__device__ __forceinline__ float leaky(float v) {
    return v > 0.f ? v : NEG_SLOPE * v;
}

__device__ __forceinline__ float rl_f(float v, int lane) {
    return __uint_as_float(__builtin_amdgcn_readlane(__float_as_uint(v), lane));
}
__device__ __forceinline__ int rl_i(int v, int lane) {
    return __builtin_amdgcn_readlane(v, lane);
}

__device__ __forceinline__ void edge_src_dst(const int* ei, int e, int& src, int& dst) {
    if (e < N_EDGES) { src = ei[e]; dst = ei[N_EDGES + e]; }
    else             { src = dst = e - N_EDGES; }
}

// ================= CSR build: two-level radix bucket =================
// Pass A: per-block coarse histogram (bin = dst>>8)
__global__ void k_chist(const int* __restrict__ ei, int* __restrict__ bh) {
    __shared__ int h[NBIN];
    for (int i = threadIdx.x; i < NBIN; i += 256) h[i] = 0;
    __syncthreads();
    int base = blockIdx.x * CHUNK;
    int lim = min(base + CHUNK, ETOT);
    for (int e = base + threadIdx.x; e < lim; e += 256) {
        int s, d; edge_src_dst(ei, e, s, d);
        atomicAdd(&h[d >> 8], 1);
    }
    __syncthreads();
    for (int i = threadIdx.x; i < NBIN; i += 256)
        bh[i * B_COARSE + blockIdx.x] = h[i];
}

// Pass B: in-place per-bin scan over blocks; exclusive scan over bin totals
__global__ void k_cscan(int* __restrict__ bh, int* __restrict__ binoff) {
    __shared__ int s[256];
    int t = threadIdx.x;
    int run = 0;
    if (t < NBIN) {
        for (int b = 0; b < B_COARSE; ++b) {
            int v = bh[t * B_COARSE + b];
            bh[t * B_COARSE + b] = run;      // now: within-bin start for this block
            run += v;
        }
    }
    int v = (t < NBIN) ? run : 0;
    int x = v;
    s[t] = x;
    __syncthreads();
#pragma unroll
    for (int o = 1; o < 256; o <<= 1) {
        int tt = (t >= o) ? s[t - o] : 0;
        __syncthreads();
        x += tt;
        s[t] = x;
        __syncthreads();
    }
    if (t < NBIN) binoff[t] = x - v;
    if (t == 255) binoff[NBIN] = x;          // == ETOT
}

// Pass C: coarse scatter of packed (src<<8 | dst&255)
__global__ void k_cscatter(const int* __restrict__ ei, const int* __restrict__ bh,
                           const int* __restrict__ binoff, unsigned* __restrict__ ebin) {
    __shared__ int cur[NBIN];
    for (int i = threadIdx.x; i < NBIN; i += 256)
        cur[i] = bh[i * B_COARSE + blockIdx.x] + binoff[i];
    __syncthreads();
    int base = blockIdx.x * CHUNK;
    int lim = min(base + CHUNK, ETOT);
    for (int e = base + threadIdx.x; e < lim; e += 256) {
        int s, d; edge_src_dst(ei, e, s, d);
        int pos = atomicAdd(&cur[d >> 8], 1);
        ebin[pos] = ((unsigned)s << 8) | (unsigned)(d & 255);
    }
}

// Pass D: per-bin fine counting sort -> rowstart + csr_src (all writes bin-local)
__global__ void k_fine(const unsigned* __restrict__ ebin, const int* __restrict__ binoff,
                       int* __restrict__ rowstart, int* __restrict__ csr_src) {
    __shared__ int h[256];
    __shared__ int cur[256];
    int bin = blockIdx.x;
    int beg = binoff[bin], end = binoff[bin + 1];
    int t = threadIdx.x;
    h[t] = 0;
    __syncthreads();
    for (int i = beg + t; i < end; i += 256)
        atomicAdd(&h[ebin[i] & 255u], 1);
    __syncthreads();
    int v = h[t];
    int x = v;
    cur[t] = x;
    __syncthreads();
#pragma unroll
    for (int o = 1; o < 256; o <<= 1) {
        int tt = (t >= o) ? cur[t - o] : 0;
        __syncthreads();
        x += tt;
        cur[t] = x;
        __syncthreads();
    }
    int start = beg + x - v;                 // exclusive
    int node = bin * 256 + t;
    if (node < N_NODES) rowstart[node] = start;
    if (bin == NBIN - 1 && t == 0) rowstart[N_NODES] = ETOT;
    cur[t] = start;
    __syncthreads();
    for (int i = beg + t; i < end; i += 256) {
        unsigned p = ebin[i];
        int pos = atomicAdd(&cur[p & 255u], 1);
        csr_src[pos] = (int)(p >> 8);
    }
}

// ============ Layer 1 node transform: h1 = x@W1, alpha logits ============
__global__ void k_node1(const float* __restrict__ x, const float* __restrict__ W1,
                        const float* __restrict__ a_src1, const float* __restrict__ a_dst1,
                        float* __restrict__ h1, float* __restrict__ as1,
                        float* __restrict__ ad1) {
    int node = blockIdx.x * 4 + (threadIdx.x >> 6);
    if (node >= N_NODES) return;
    int j = threadIdx.x & 63;
    int head = j >> 5;

    float h = 0.f;
#pragma unroll
    for (int k = 0; k < 6; ++k)
        h += x[node * 6 + k] * W1[k * 64 + j];
    h1[node * 64 + j] = h;

    float s = h * a_src1[j];
    float d = h * a_dst1[j];
#pragma unroll
    for (int m = 1; m < 32; m <<= 1) {
        s += __shfl_xor(s, m);
        d += __shfl_xor(d, m);
    }
    if ((j & 31) == 0) {
        as1[node * 2 + head] = s;   // interleaved (node,head) -> float2-gatherable
        ad1[node * 2 + head] = d;
    }
}

// ============ Layer 1 fused softmax(no-max) + aggregate: one wave per dst ============
__global__ void k_gat1(const int* __restrict__ csr_src, const int* __restrict__ rowstart,
                       const float* __restrict__ as1, const float* __restrict__ ad1,
                       const float* __restrict__ h1, const float* __restrict__ b1,
                       float* __restrict__ o1) {
    int node = blockIdx.x * 4 + (threadIdx.x >> 6);
    if (node >= N_NODES) return;
    int j = threadIdx.x & 63;
    int head = j >> 5;
    int beg = rowstart[node], end = rowstart[node + 1];
    float adv0 = ad1[node * 2 + 0];
    float adv1 = ad1[node * 2 + 1];

    float acc = 0.f, dp0 = 0.f, dp1 = 0.f;
    for (int base = beg; base < end; base += 64) {
        int idx = base + j;
        int cnt = min(64, end - base);
        float w0 = 0.f, w1 = 0.f;
        int s = 0;
        if (idx < end) {
            s = csr_src[idx];
            float2 a = ((const float2*)as1)[s];
            w0 = __expf(leaky(a.x + adv0));   // no max subtraction: logits are O(1)
            w1 = __expf(leaky(a.y + adv1));
            dp0 += w0;
            dp1 += w1;
        }
        int k = 0;
        for (; k + 16 <= cnt; k += 16) {
#pragma unroll
            for (int u = 0; u < 16; ++u) {
                int   sk  = rl_i(s,  k + u);     // uniform index -> v_readlane (no LDS)
                float w0k = rl_f(w0, k + u);
                float w1k = rl_f(w1, k + u);
                acc += (head ? w1k : w0k) * h1[sk * 64 + j];
            }
        }
        for (; k < cnt; ++k) {
            int   sk  = rl_i(s,  k);
            float w0k = rl_f(w0, k);
            float w1k = rl_f(w1, k);
            acc += (head ? w1k : w0k) * h1[sk * 64 + j];
        }
    }
#pragma unroll
    for (int o = 32; o; o >>= 1) {
        dp0 += __shfl_xor(dp0, o);
        dp1 += __shfl_xor(dp1, o);
    }
    float den = head ? dp1 : dp0;
    float v = acc / den + b1[j];
    o1[node * 64 + j] = v > 0.f ? v : 0.f;    // bias + relu fused
}

// ============ Layer 2 node transform: h2 = o1@W2, alpha logits ============
__global__ void k_node2(const float* __restrict__ o1, const float* __restrict__ W2,
                        const float* __restrict__ a_src2, const float* __restrict__ a_dst2,
                        float* __restrict__ h2, float* __restrict__ as2,
                        float* __restrict__ ad2) {
    __shared__ float W2s[64 * 32];
    for (int i = threadIdx.x; i < 64 * 32; i += 256)
        W2s[i] = W2[i];
    __syncthreads();

    int node = blockIdx.x * 8 + (threadIdx.x >> 5);
    if (node >= N_NODES) return;
    int j = threadIdx.x & 31;

    float acc = 0.f;
#pragma unroll
    for (int k = 0; k < 64; ++k)
        acc += o1[node * 64 + k] * W2s[k * 32 + j];
    h2[node * 32 + j] = acc;

    float s = acc * a_src2[j];
    float d = acc * a_dst2[j];
#pragma unroll
    for (int m = 1; m < 32; m <<= 1) {
        s += __shfl_xor(s, m, 32);
        d += __shfl_xor(d, m, 32);
    }
    if (j == 0) {
        as2[node] = s;
        ad2[node] = d;
    }
}

// ============ Layer 2 fused softmax(no-max) + aggregate + output head ============
__global__ void k_gat2(const int* __restrict__ csr_src, const int* __restrict__ rowstart,
                       const float* __restrict__ as2, const float* __restrict__ ad2,
                       const float* __restrict__ h2, const float* __restrict__ b2,
                       const float* __restrict__ Wout, const float* __restrict__ bout,
                       float* __restrict__ out) {
    int node = blockIdx.x * 4 + (threadIdx.x >> 6);
    if (node >= N_NODES) return;
    int j = threadIdx.x & 63;
    int f = j & 31;
    int half = j >> 5;
    int beg = rowstart[node], end = rowstart[node + 1];
    float adv = ad2[node];

    float acc = 0.f, dp = 0.f;
    for (int base = beg; base < end; base += 64) {
        int idx = base + j;
        int cnt = min(64, end - base);
        float w = 0.f;
        int s = 0;
        if (idx < end) {
            s = csr_src[idx];
            w = __expf(leaky(as2[s] + adv));
            dp += w;
        }
        int k = 0;
        for (; k + 8 <= cnt; k += 8) {
#pragma unroll
            for (int u = 0; u < 4; ++u) {      // 2 edges per step
                int   sa = rl_i(s, k + 2 * u);
                int   sb = rl_i(s, k + 2 * u + 1);
                float wa = rl_f(w, k + 2 * u);
                float wb = rl_f(w, k + 2 * u + 1);
                int   sk = half ? sb : sa;
                float wk = half ? wb : wa;
                acc += wk * h2[sk * 32 + f];
            }
        }
        for (; k + 2 <= cnt; k += 2) {
            int   sa = rl_i(s, k);
            int   sb = rl_i(s, k + 1);
            float wa = rl_f(w, k);
            float wb = rl_f(w, k + 1);
            int   sk = half ? sb : sa;
            float wk = half ? wb : wa;
            acc += wk * h2[sk * 32 + f];
        }
        if (k < cnt) {                          // odd tail edge
            int   sa = rl_i(s, k);
            float wa = rl_f(w, k);
            if (half == 0) acc += wa * h2[sa * 32 + f];
        }
    }
#pragma unroll
    for (int o = 32; o; o >>= 1)
        dp += __shfl_xor(dp, o);
    acc += __shfl_xor(acc, 32);

    float v = acc / dp + b2[f];
    v = v > 0.f ? v : 0.f;
    float t = v * Wout[f];
#pragma unroll
    for (int o = 16; o; o >>= 1)
        t += __shfl_xor(t, o);
    if (j == 0)
        out[node] = 1.f / (1.f + __expf(-(t + bout[0])));
}

extern "C" void kernel_launch(void* const* d_in, const int* in_sizes, int n_in,
                              void* d_out, int out_size, void* d_ws, size_t ws_size,
                              hipStream_t stream) {
    const float* x    = (const float*)d_in[0];
    const int*   ei   = (const int*)  d_in[1];
    const float* W1   = (const float*)d_in[2];
    const float* asw1 = (const float*)d_in[3];
    const float* adw1 = (const float*)d_in[4];
    const float* b1   = (const float*)d_in[5];
    const float* W2   = (const float*)d_in[6];
    const float* asw2 = (const float*)d_in[7];
    const float* adw2 = (const float*)d_in[8];
    const float* b2   = (const float*)d_in[9];
    const float* Wout = (const float*)d_in[10];
    const float* bout = (const float*)d_in[11];
    float* out = (float*)d_out;

    char* p = (char*)d_ws;
    auto carve = [&](size_t bytes) {
        void* r = (void*)p;
        p += (bytes + 255) & ~size_t(255);
        return r;
    };
    float*    h1       = (float*)   carve((size_t)N_NODES * 64 * 4);
    float*    o1       = (float*)   carve((size_t)N_NODES * 64 * 4);
    float*    h2       = (float*)   carve((size_t)N_NODES * 32 * 4);
    float*    as1      = (float*)   carve((size_t)N_NODES * 2 * 4);
    float*    ad1      = (float*)   carve((size_t)N_NODES * 2 * 4);
    float*    as2      = (float*)   carve((size_t)N_NODES * 4);
    float*    ad2      = (float*)   carve((size_t)N_NODES * 4);
    int*      bh       = (int*)     carve((size_t)NBIN * B_COARSE * 4);
    int*      binoff   = (int*)     carve((size_t)(NBIN + 1) * 4);
    unsigned* ebin     = (unsigned*)carve((size_t)ETOT * 4);
    int*      rowstart = (int*)     carve((size_t)(N_NODES + 1) * 4);
    int*      csr_src  = (int*)     carve((size_t)ETOT * 4);

    const int TB = 256;

    // ---- CSR build: coarse radix + per-bin fine sort ----
    k_chist   <<<B_COARSE, TB, 0, stream>>>(ei, bh);
    k_cscan   <<<1, TB, 0, stream>>>(bh, binoff);
    k_cscatter<<<B_COARSE, TB, 0, stream>>>(ei, bh, binoff, ebin);
    k_fine    <<<NBIN, TB, 0, stream>>>(ebin, binoff, rowstart, csr_src);

    // ---- layer 1 ----
    k_node1<<<(N_NODES + 3) / 4, TB, 0, stream>>>(x, W1, asw1, adw1, h1, as1, ad1);
    k_gat1 <<<(N_NODES + 3) / 4, TB, 0, stream>>>(csr_src, rowstart, as1, ad1, h1, b1, o1);

    // ---- layer 2 ----
    k_node2<<<(N_NODES + 7) / 8, TB, 0, stream>>>(o1, W2, asw2, adw2, h2, as2, ad2);
    k_gat2 <<<(N_NODES + 3) / 4, TB, 0, stream>>>(csr_src, rowstart, as2, ad2, h2, b2, Wout, bout, out);
}

// Round 5
// 117.631 us; speedup vs baseline: 4.7936x; 1.2505x over previous
//
#include <hip/hip_runtime.h>

#define N_NODES 50000
#define N_EDGES 800000
#define ETOT    (N_EDGES + N_NODES)   // edges + self loops
#define NEG_SLOPE 0.2f
#define NBIN    ((N_NODES + 255) / 256)     // 196 coarse bins (dst>>8)
#define CHUNK   4096
#define B_COARSE ((ETOT + CHUNK - 1) / CHUNK)  // 208 blocks

__device__ __forceinline__ float leaky(float v) {
    return v > 0.f ? v : NEG_SLOPE * v;
}

__device__ __forceinline__ void edge_src_dst(const int* ei, int e, int& src, int& dst) {
    if (e < N_EDGES) { src = ei[e]; dst = ei[N_EDGES + e]; }
    else             { src = dst = e - N_EDGES; }
}

// ================= CSR build: two-level radix bucket =================
__global__ void k_chist(const int* __restrict__ ei, int* __restrict__ bh) {
    __shared__ int h[NBIN];
    for (int i = threadIdx.x; i < NBIN; i += 256) h[i] = 0;
    __syncthreads();
    int base = blockIdx.x * CHUNK;
    int lim = min(base + CHUNK, ETOT);
    for (int e = base + threadIdx.x; e < lim; e += 256) {
        int s, d; edge_src_dst(ei, e, s, d);
        atomicAdd(&h[d >> 8], 1);
    }
    __syncthreads();
    for (int i = threadIdx.x; i < NBIN; i += 256)
        bh[i * B_COARSE + blockIdx.x] = h[i];
}

__global__ void k_cscan(int* __restrict__ bh, int* __restrict__ binoff) {
    __shared__ int s[256];
    int t = threadIdx.x;
    int run = 0;
    if (t < NBIN) {
        for (int b = 0; b < B_COARSE; ++b) {
            int v = bh[t * B_COARSE + b];
            bh[t * B_COARSE + b] = run;
            run += v;
        }
    }
    int v = (t < NBIN) ? run : 0;
    int x = v;
    s[t] = x;
    __syncthreads();
#pragma unroll
    for (int o = 1; o < 256; o <<= 1) {
        int tt = (t >= o) ? s[t - o] : 0;
        __syncthreads();
        x += tt;
        s[t] = x;
        __syncthreads();
    }
    if (t < NBIN) binoff[t] = x - v;
    if (t == 255) binoff[NBIN] = x;
}

__global__ void k_cscatter(const int* __restrict__ ei, const int* __restrict__ bh,
                           const int* __restrict__ binoff, unsigned* __restrict__ ebin) {
    __shared__ int cur[NBIN];
    for (int i = threadIdx.x; i < NBIN; i += 256)
        cur[i] = bh[i * B_COARSE + blockIdx.x] + binoff[i];
    __syncthreads();
    int base = blockIdx.x * CHUNK;
    int lim = min(base + CHUNK, ETOT);
    for (int e = base + threadIdx.x; e < lim; e += 256) {
        int s, d; edge_src_dst(ei, e, s, d);
        int pos = atomicAdd(&cur[d >> 8], 1);
        ebin[pos] = ((unsigned)s << 8) | (unsigned)(d & 255);
    }
}

__global__ void k_fine(const unsigned* __restrict__ ebin, const int* __restrict__ binoff,
                       int* __restrict__ rowstart, int* __restrict__ csr_src) {
    __shared__ int h[256];
    __shared__ int cur[256];
    int bin = blockIdx.x;
    int beg = binoff[bin], end = binoff[bin + 1];
    int t = threadIdx.x;
    h[t] = 0;
    __syncthreads();
    for (int i = beg + t; i < end; i += 256)
        atomicAdd(&h[ebin[i] & 255u], 1);
    __syncthreads();
    int v = h[t];
    int x = v;
    cur[t] = x;
    __syncthreads();
#pragma unroll
    for (int o = 1; o < 256; o <<= 1) {
        int tt = (t >= o) ? cur[t - o] : 0;
        __syncthreads();
        x += tt;
        cur[t] = x;
        __syncthreads();
    }
    int start = beg + x - v;
    int node = bin * 256 + t;
    if (node < N_NODES) rowstart[node] = start;
    if (bin == NBIN - 1 && t == 0) rowstart[N_NODES] = ETOT;
    cur[t] = start;
    __syncthreads();
    for (int i = beg + t; i < end; i += 256) {
        unsigned p = ebin[i];
        int pos = atomicAdd(&cur[p & 255u], 1);
        csr_src[pos] = (int)(p >> 8);
    }
}

// ============ Layer 1 logits: as1/ad1 from h = x@W1 (h not stored) ============
__global__ void k_node1(const float* __restrict__ x, const float* __restrict__ W1,
                        const float* __restrict__ a_src1, const float* __restrict__ a_dst1,
                        float* __restrict__ as1, float* __restrict__ ad1) {
    int node = blockIdx.x * 4 + (threadIdx.x >> 6);
    if (node >= N_NODES) return;
    int j = threadIdx.x & 63;
    int head = j >> 5;

    float h = 0.f;
#pragma unroll
    for (int k = 0; k < 6; ++k)
        h += x[node * 6 + k] * W1[k * 64 + j];

    float s = h * a_src1[j];
    float d = h * a_dst1[j];
#pragma unroll
    for (int m = 1; m < 32; m <<= 1) {
        s += __shfl_xor(s, m);
        d += __shfl_xor(d, m);
    }
    if ((j & 31) == 0) {
        as1[node * 2 + head] = s;   // interleaved (node,head) -> float2-gatherable
        ad1[node * 2 + head] = d;
    }
}

// ============ Layer 1 fused: aggregate x (6-dim!) then apply W1 per node ============
// Σ_e w_e h1[src] = (Σ_e w_e x[src]) @ W1.  One 16-lane group per node.
__global__ void k_gat1(const int* __restrict__ csr_src, const int* __restrict__ rowstart,
                       const float* __restrict__ as1, const float* __restrict__ ad1,
                       const float* __restrict__ x, const float* __restrict__ W1,
                       const float* __restrict__ b1, float* __restrict__ o1) {
    int node = blockIdx.x * 16 + (threadIdx.x >> 4);
    if (node >= N_NODES) return;
    int l = threadIdx.x & 15;

    // preload W1 cols l, l+16 (head0) and l+32, l+48 (head1), plus b1
    float p[4][6];
    float bv[4];
#pragma unroll
    for (int m = 0; m < 4; ++m) {
        int c = l + 16 * m;
#pragma unroll
        for (int k = 0; k < 6; ++k)
            p[m][k] = W1[k * 64 + c];
        bv[m] = b1[c];
    }

    int beg = rowstart[node], end = rowstart[node + 1];
    float2 adv = ((const float2*)ad1)[node];

    float a0 = 0, a1 = 0, a2 = 0, a3 = 0, a4 = 0, a5 = 0;   // head0: Σ w0*x
    float c0 = 0, c1 = 0, c2 = 0, c3 = 0, c4 = 0, c5 = 0;   // head1: Σ w1*x
    float dp0 = 0, dp1 = 0;
    for (int i = beg + l; i < end; i += 16) {
        int s = csr_src[i];
        float2 aa = ((const float2*)as1)[s];
        float w0 = __expf(leaky(aa.x + adv.x));   // logits O(1): no max needed
        float w1 = __expf(leaky(aa.y + adv.y));
        dp0 += w0;
        dp1 += w1;
        const float2* xs = (const float2*)(x + s * 6);
        float2 u = xs[0], v = xs[1], w = xs[2];
        a0 += w0 * u.x; a1 += w0 * u.y; a2 += w0 * v.x;
        a3 += w0 * v.y; a4 += w0 * w.x; a5 += w0 * w.y;
        c0 += w1 * u.x; c1 += w1 * u.y; c2 += w1 * v.x;
        c3 += w1 * v.y; c4 += w1 * w.x; c5 += w1 * w.y;
    }
    // butterfly reduce 14 values within the 16-lane group
#pragma unroll
    for (int o = 8; o; o >>= 1) {
        a0 += __shfl_xor(a0, o); a1 += __shfl_xor(a1, o); a2 += __shfl_xor(a2, o);
        a3 += __shfl_xor(a3, o); a4 += __shfl_xor(a4, o); a5 += __shfl_xor(a5, o);
        c0 += __shfl_xor(c0, o); c1 += __shfl_xor(c1, o); c2 += __shfl_xor(c2, o);
        c3 += __shfl_xor(c3, o); c4 += __shfl_xor(c4, o); c5 += __shfl_xor(c5, o);
        dp0 += __shfl_xor(dp0, o); dp1 += __shfl_xor(dp1, o);
    }
    float inv0 = 1.f / dp0;
    float inv1 = 1.f / dp1;
    float* ob = o1 + (size_t)node * 64;
#pragma unroll
    for (int m = 0; m < 4; ++m) {
        float dot;
        if (m < 2)
            dot = a0 * p[m][0] + a1 * p[m][1] + a2 * p[m][2]
                + a3 * p[m][3] + a4 * p[m][4] + a5 * p[m][5];
        else
            dot = c0 * p[m][0] + c1 * p[m][1] + c2 * p[m][2]
                + c3 * p[m][3] + c4 * p[m][4] + c5 * p[m][5];
        float v = dot * (m < 2 ? inv0 : inv1) + bv[m];
        ob[l + 16 * m] = v > 0.f ? v : 0.f;    // bias + relu fused
    }
}

// ============ Layer 2 node transform: h2 = o1@W2, alpha logits ============
__global__ void k_node2(const float* __restrict__ o1, const float* __restrict__ W2,
                        const float* __restrict__ a_src2, const float* __restrict__ a_dst2,
                        float* __restrict__ h2, float* __restrict__ as2,
                        float* __restrict__ ad2) {
    __shared__ float W2s[64 * 32];
    for (int i = threadIdx.x; i < 64 * 32; i += 256)
        W2s[i] = W2[i];
    __syncthreads();

    int node = blockIdx.x * 8 + (threadIdx.x >> 5);
    if (node >= N_NODES) return;
    int j = threadIdx.x & 31;

    float acc = 0.f;
#pragma unroll
    for (int k = 0; k < 64; ++k)
        acc += o1[node * 64 + k] * W2s[k * 32 + j];
    h2[node * 32 + j] = acc;

    float s = acc * a_src2[j];
    float d = acc * a_dst2[j];
#pragma unroll
    for (int m = 1; m < 32; m <<= 1) {
        s += __shfl_xor(s, m, 32);
        d += __shfl_xor(d, m, 32);
    }
    if (j == 0) {
        as2[node] = s;
        ad2[node] = d;
    }
}

// ============ Layer 2 fused softmax(no-max) + aggregate + output head ============
__global__ void k_gat2(const int* __restrict__ csr_src, const int* __restrict__ rowstart,
                       const float* __restrict__ as2, const float* __restrict__ ad2,
                       const float* __restrict__ h2, const float* __restrict__ b2,
                       const float* __restrict__ Wout, const float* __restrict__ bout,
                       float* __restrict__ out) {
    int node = blockIdx.x * 4 + (threadIdx.x >> 6);
    if (node >= N_NODES) return;
    int j = threadIdx.x & 63;
    int f = j & 31;
    int half = j >> 5;
    int beg = rowstart[node], end = rowstart[node + 1];
    float adv = ad2[node];

    float acc = 0.f, dp = 0.f;
    for (int base = beg; base < end; base += 64) {
        int idx = base + j;
        int cnt = min(64, end - base);
        float w = 0.f;
        int s = 0;
        if (idx < end) {
            s = csr_src[idx];
            w = __expf(leaky(as2[s] + adv));
            dp += w;
        }
        int k = 0;
        for (; k + 8 <= cnt; k += 8) {
#pragma unroll
            for (int u = 0; u < 4; ++u) {      // 2 edges per step via lane halves
                int   sk = __shfl(s, k + 2 * u + half);
                float wk = __shfl(w, k + 2 * u + half);
                acc += wk * h2[sk * 32 + f];
            }
        }
        for (; k + 2 <= cnt; k += 2) {
            int   sk = __shfl(s, k + half);
            float wk = __shfl(w, k + half);
            acc += wk * h2[sk * 32 + f];
        }
        if (k < cnt) {                          // odd tail edge
            int   sk = __shfl(s, k);
            float wk = __shfl(w, k);
            if (half == 0) acc += wk * h2[sk * 32 + f];
        }
    }
#pragma unroll
    for (int o = 32; o; o >>= 1)
        dp += __shfl_xor(dp, o);
    acc += __shfl_xor(acc, 32);

    float v = acc / dp + b2[f];
    v = v > 0.f ? v : 0.f;
    float t = v * Wout[f];
#pragma unroll
    for (int o = 16; o; o >>= 1)
        t += __shfl_xor(t, o);
    if (j == 0)
        out[node] = 1.f / (1.f + __expf(-(t + bout[0])));
}

extern "C" void kernel_launch(void* const* d_in, const int* in_sizes, int n_in,
                              void* d_out, int out_size, void* d_ws, size_t ws_size,
                              hipStream_t stream) {
    const float* x    = (const float*)d_in[0];
    const int*   ei   = (const int*)  d_in[1];
    const float* W1   = (const float*)d_in[2];
    const float* asw1 = (const float*)d_in[3];
    const float* adw1 = (const float*)d_in[4];
    const float* b1   = (const float*)d_in[5];
    const float* W2   = (const float*)d_in[6];
    const float* asw2 = (const float*)d_in[7];
    const float* adw2 = (const float*)d_in[8];
    const float* b2   = (const float*)d_in[9];
    const float* Wout = (const float*)d_in[10];
    const float* bout = (const float*)d_in[11];
    float* out = (float*)d_out;

    char* p = (char*)d_ws;
    auto carve = [&](size_t bytes) {
        void* r = (void*)p;
        p += (bytes + 255) & ~size_t(255);
        return r;
    };
    float*    o1       = (float*)   carve((size_t)N_NODES * 64 * 4);
    float*    h2       = (float*)   carve((size_t)N_NODES * 32 * 4);
    float*    as1      = (float*)   carve((size_t)N_NODES * 2 * 4);
    float*    ad1      = (float*)   carve((size_t)N_NODES * 2 * 4);
    float*    as2      = (float*)   carve((size_t)N_NODES * 4);
    float*    ad2      = (float*)   carve((size_t)N_NODES * 4);
    int*      bh       = (int*)     carve((size_t)NBIN * B_COARSE * 4);
    int*      binoff   = (int*)     carve((size_t)(NBIN + 1) * 4);
    unsigned* ebin     = (unsigned*)carve((size_t)ETOT * 4);
    int*      rowstart = (int*)     carve((size_t)(N_NODES + 1) * 4);
    int*      csr_src  = (int*)     carve((size_t)ETOT * 4);

    const int TB = 256;

    // ---- CSR build: coarse radix + per-bin fine sort ----
    k_chist   <<<B_COARSE, TB, 0, stream>>>(ei, bh);
    k_cscan   <<<1, TB, 0, stream>>>(bh, binoff);
    k_cscatter<<<B_COARSE, TB, 0, stream>>>(ei, bh, binoff, ebin);
    k_fine    <<<NBIN, TB, 0, stream>>>(ebin, binoff, rowstart, csr_src);

    // ---- layer 1 ----
    k_node1<<<(N_NODES + 3) / 4, TB, 0, stream>>>(x, W1, asw1, adw1, as1, ad1);
    k_gat1 <<<(N_NODES + 15) / 16, TB, 0, stream>>>(csr_src, rowstart, as1, ad1, x, W1, b1, o1);

    // ---- layer 2 ----
    k_node2<<<(N_NODES + 7) / 8, TB, 0, stream>>>(o1, W2, asw2, adw2, h2, as2, ad2);
    k_gat2 <<<(N_NODES + 3) / 4, TB, 0, stream>>>(csr_src, rowstart, as2, ad2, h2, b2, Wout, bout, out);
}

// Round 6
// 106.801 us; speedup vs baseline: 5.2798x; 1.1014x over previous
//
#include <hip/hip_runtime.h>
#include <hip/hip_fp16.h>

#define N_NODES 50000
#define N_EDGES 800000
#define ETOT    (N_EDGES + N_NODES)   // edges + self loops
#define NEG_SLOPE 0.2f
#define NBIN    ((N_NODES + 255) / 256)     // 196 coarse bins (dst>>8)
#define CHUNK   4096
#define B_COARSE ((ETOT + CHUNK - 1) / CHUNK)  // 208 blocks
#define G_NODE1 ((N_NODES + 3) / 4)            // 12500 blocks for node1 part

__device__ __forceinline__ float leaky(float v) {
    return v > 0.f ? v : NEG_SLOPE * v;
}

__device__ __forceinline__ void edge_src_dst(const int* ei, int e, int& src, int& dst) {
    if (e < N_EDGES) { src = ei[e]; dst = ei[N_EDGES + e]; }
    else             { src = dst = e - N_EDGES; }
}

// ======== Fused: layer-1 logits (blocks < G_NODE1) + coarse histogram ========
__global__ void k_pre(const float* __restrict__ x, const float* __restrict__ W1,
                      const float* __restrict__ a_src1, const float* __restrict__ a_dst1,
                      float* __restrict__ as1, float* __restrict__ ad1,
                      const int* __restrict__ ei, int* __restrict__ bh) {
    __shared__ int h[NBIN];
    if (blockIdx.x < G_NODE1) {
        // ---- node1: as1/ad1 from h = x@W1 (h not stored) ----
        int node = blockIdx.x * 4 + (threadIdx.x >> 6);
        if (node >= N_NODES) return;
        int j = threadIdx.x & 63;
        int head = j >> 5;
        float hv = 0.f;
#pragma unroll
        for (int k = 0; k < 6; ++k)
            hv += x[node * 6 + k] * W1[k * 64 + j];
        float s = hv * a_src1[j];
        float d = hv * a_dst1[j];
#pragma unroll
        for (int m = 1; m < 32; m <<= 1) {
            s += __shfl_xor(s, m);
            d += __shfl_xor(d, m);
        }
        if ((j & 31) == 0) {
            as1[node * 2 + head] = s;
            ad1[node * 2 + head] = d;
        }
    } else {
        // ---- coarse histogram (bin = dst>>8), bh transposed [block][bin] ----
        int b = blockIdx.x - G_NODE1;
        for (int i = threadIdx.x; i < NBIN; i += 256) h[i] = 0;
        __syncthreads();
        int base = b * CHUNK;
        int lim = min(base + CHUNK, ETOT);
        for (int e = base + threadIdx.x; e < lim; e += 256) {
            int s, d; edge_src_dst(ei, e, s, d);
            atomicAdd(&h[d >> 8], 1);
        }
        __syncthreads();
        for (int i = threadIdx.x; i < NBIN; i += 256)
            bh[b * NBIN + i] = h[i];
    }
}

// per-bin running offsets over blocks (coalesced) + exclusive scan of totals
__global__ void k_cscan(int* __restrict__ bh, int* __restrict__ binoff) {
    __shared__ int s[256];
    int t = threadIdx.x;
    int run = 0;
    if (t < NBIN) {
        for (int b = 0; b < B_COARSE; ++b) {
            int v = bh[b * NBIN + t];
            bh[b * NBIN + t] = run;
            run += v;
        }
    }
    int v = (t < NBIN) ? run : 0;
    int x = v;
    s[t] = x;
    __syncthreads();
#pragma unroll
    for (int o = 1; o < 256; o <<= 1) {
        int tt = (t >= o) ? s[t - o] : 0;
        __syncthreads();
        x += tt;
        s[t] = x;
        __syncthreads();
    }
    if (t < NBIN) binoff[t] = x - v;
    if (t == 255) binoff[NBIN] = x;
}

__global__ void k_cscatter(const int* __restrict__ ei, const int* __restrict__ bh,
                           const int* __restrict__ binoff, unsigned* __restrict__ ebin) {
    __shared__ int cur[NBIN];
    for (int i = threadIdx.x; i < NBIN; i += 256)
        cur[i] = bh[blockIdx.x * NBIN + i] + binoff[i];
    __syncthreads();
    int base = blockIdx.x * CHUNK;
    int lim = min(base + CHUNK, ETOT);
    for (int e = base + threadIdx.x; e < lim; e += 256) {
        int s, d; edge_src_dst(ei, e, s, d);
        int pos = atomicAdd(&cur[d >> 8], 1);
        ebin[pos] = ((unsigned)s << 8) | (unsigned)(d & 255);
    }
}

__global__ void k_fine(const unsigned* __restrict__ ebin, const int* __restrict__ binoff,
                       int* __restrict__ rowstart, int* __restrict__ csr_src) {
    __shared__ int h[256];
    __shared__ int cur[256];
    int bin = blockIdx.x;
    int beg = binoff[bin], end = binoff[bin + 1];
    int t = threadIdx.x;
    h[t] = 0;
    __syncthreads();
    for (int i = beg + t; i < end; i += 256)
        atomicAdd(&h[ebin[i] & 255u], 1);
    __syncthreads();
    int v = h[t];
    int x = v;
    cur[t] = x;
    __syncthreads();
#pragma unroll
    for (int o = 1; o < 256; o <<= 1) {
        int tt = (t >= o) ? cur[t - o] : 0;
        __syncthreads();
        x += tt;
        cur[t] = x;
        __syncthreads();
    }
    int start = beg + x - v;
    int node = bin * 256 + t;
    if (node < N_NODES) rowstart[node] = start;
    if (bin == NBIN - 1 && t == 0) rowstart[N_NODES] = ETOT;
    cur[t] = start;
    __syncthreads();
    for (int i = beg + t; i < end; i += 256) {
        unsigned p = ebin[i];
        int pos = atomicAdd(&cur[p & 255u], 1);
        csr_src[pos] = (int)(p >> 8);
    }
}

// ============ Layer 1 fused: aggregate x (6-dim) then apply W1 per node ============
__global__ void k_gat1(const int* __restrict__ csr_src, const int* __restrict__ rowstart,
                       const float* __restrict__ as1, const float* __restrict__ ad1,
                       const float* __restrict__ x, const float* __restrict__ W1,
                       const float* __restrict__ b1, float* __restrict__ o1) {
    int node = blockIdx.x * 16 + (threadIdx.x >> 4);
    if (node >= N_NODES) return;
    int l = threadIdx.x & 15;

    float p[4][6];
    float bv[4];
#pragma unroll
    for (int m = 0; m < 4; ++m) {
        int c = l + 16 * m;
#pragma unroll
        for (int k = 0; k < 6; ++k)
            p[m][k] = W1[k * 64 + c];
        bv[m] = b1[c];
    }

    int beg = rowstart[node], end = rowstart[node + 1];
    float2 adv = ((const float2*)ad1)[node];

    float a0 = 0, a1 = 0, a2 = 0, a3 = 0, a4 = 0, a5 = 0;
    float c0 = 0, c1 = 0, c2 = 0, c3 = 0, c4 = 0, c5 = 0;
    float dp0 = 0, dp1 = 0;
    for (int i = beg + l; i < end; i += 16) {
        int s = csr_src[i];
        float2 aa = ((const float2*)as1)[s];
        float w0 = __expf(leaky(aa.x + adv.x));
        float w1 = __expf(leaky(aa.y + adv.y));
        dp0 += w0;
        dp1 += w1;
        const float2* xs = (const float2*)(x + s * 6);
        float2 u = xs[0], v = xs[1], w = xs[2];
        a0 += w0 * u.x; a1 += w0 * u.y; a2 += w0 * v.x;
        a3 += w0 * v.y; a4 += w0 * w.x; a5 += w0 * w.y;
        c0 += w1 * u.x; c1 += w1 * u.y; c2 += w1 * v.x;
        c3 += w1 * v.y; c4 += w1 * w.x; c5 += w1 * w.y;
    }
#pragma unroll
    for (int o = 8; o; o >>= 1) {
        a0 += __shfl_xor(a0, o); a1 += __shfl_xor(a1, o); a2 += __shfl_xor(a2, o);
        a3 += __shfl_xor(a3, o); a4 += __shfl_xor(a4, o); a5 += __shfl_xor(a5, o);
        c0 += __shfl_xor(c0, o); c1 += __shfl_xor(c1, o); c2 += __shfl_xor(c2, o);
        c3 += __shfl_xor(c3, o); c4 += __shfl_xor(c4, o); c5 += __shfl_xor(c5, o);
        dp0 += __shfl_xor(dp0, o); dp1 += __shfl_xor(dp1, o);
    }
    float inv0 = 1.f / dp0;
    float inv1 = 1.f / dp1;
    float* ob = o1 + (size_t)node * 64;
#pragma unroll
    for (int m = 0; m < 4; ++m) {
        float dot;
        if (m < 2)
            dot = a0 * p[m][0] + a1 * p[m][1] + a2 * p[m][2]
                + a3 * p[m][3] + a4 * p[m][4] + a5 * p[m][5];
        else
            dot = c0 * p[m][0] + c1 * p[m][1] + c2 * p[m][2]
                + c3 * p[m][3] + c4 * p[m][4] + c5 * p[m][5];
        float v = dot * (m < 2 ? inv0 : inv1) + bv[m];
        ob[l + 16 * m] = v > 0.f ? v : 0.f;
    }
}

// ============ Layer 2 node transform: h2 = o1@W2 (fp16 packed), alpha logits ============
__global__ void k_node2(const float* __restrict__ o1, const float* __restrict__ W2,
                        const float* __restrict__ a_src2, const float* __restrict__ a_dst2,
                        __half* __restrict__ h2h, float* __restrict__ as2,
                        float* __restrict__ ad2) {
    __shared__ float W2s[64 * 32];
    for (int i = threadIdx.x; i < 64 * 32; i += 256)
        W2s[i] = W2[i];
    __syncthreads();

    int node = blockIdx.x * 8 + (threadIdx.x >> 5);
    if (node >= N_NODES) return;
    int j = threadIdx.x & 31;

    float acc = 0.f;
#pragma unroll
    for (int k = 0; k < 64; ++k)
        acc += o1[node * 64 + k] * W2s[k * 32 + j];
    h2h[node * 32 + j] = __float2half(acc);   // 3.2 MB total -> L2-resident

    float s = acc * a_src2[j];
    float d = acc * a_dst2[j];
#pragma unroll
    for (int m = 1; m < 32; m <<= 1) {
        s += __shfl_xor(s, m, 32);
        d += __shfl_xor(d, m, 32);
    }
    if (j == 0) {
        as2[node] = s;
        ad2[node] = d;
    }
}

// ============ Layer 2 fused softmax(no-max) + aggregate + output head ============
// one wave per node: 4 edge slots x 16 feature-pair lanes (fp16x2 gather)
__global__ void k_gat2(const int* __restrict__ csr_src, const int* __restrict__ rowstart,
                       const float* __restrict__ as2, const float* __restrict__ ad2,
                       const __half2* __restrict__ h2h, const float* __restrict__ b2,
                       const float* __restrict__ Wout, const float* __restrict__ bout,
                       float* __restrict__ out) {
    int node = blockIdx.x * 4 + (threadIdx.x >> 6);
    if (node >= N_NODES) return;
    int j = threadIdx.x & 63;
    int f = j & 15;          // feature pair (2f, 2f+1)
    int slot = j >> 4;       // edge slot 0..3
    int beg = rowstart[node], end = rowstart[node + 1];
    float adv = ad2[node];

    float accx = 0.f, accy = 0.f, dp = 0.f;
    for (int base = beg; base < end; base += 64) {
        int idx = base + j;
        float w = 0.f;
        int s = 0;
        if (idx < end) {
            s = csr_src[idx];
            w = __expf(leaky(as2[s] + adv));
            dp += w;
        }
        int cnt = min(64, end - base);
        for (int k = 0; k < cnt; k += 4) {
            int   sk = __shfl(s, k + slot);     // w=0 for lanes >= cnt -> no tail case
            float wk = __shfl(w, k + slot);
            float2 hv = __half22float2(h2h[sk * 16 + f]);
            accx += wk * hv.x;
            accy += wk * hv.y;
        }
    }
#pragma unroll
    for (int o = 32; o; o >>= 1)
        dp += __shfl_xor(dp, o);
    // fold the 4 edge slots (lanes differing in bits 4-5)
    accx += __shfl_xor(accx, 16); accy += __shfl_xor(accy, 16);
    accx += __shfl_xor(accx, 32); accy += __shfl_xor(accy, 32);

    float inv = 1.f / dp;
    float vx = accx * inv + b2[2 * f];
    float vy = accy * inv + b2[2 * f + 1];
    vx = vx > 0.f ? vx : 0.f;
    vy = vy > 0.f ? vy : 0.f;
    float t = vx * Wout[2 * f] + vy * Wout[2 * f + 1];
#pragma unroll
    for (int o = 8; o; o >>= 1)
        t += __shfl_xor(t, o);
    if (j == 0)
        out[node] = 1.f / (1.f + __expf(-(t + bout[0])));
}

extern "C" void kernel_launch(void* const* d_in, const int* in_sizes, int n_in,
                              void* d_out, int out_size, void* d_ws, size_t ws_size,
                              hipStream_t stream) {
    const float* x    = (const float*)d_in[0];
    const int*   ei   = (const int*)  d_in[1];
    const float* W1   = (const float*)d_in[2];
    const float* asw1 = (const float*)d_in[3];
    const float* adw1 = (const float*)d_in[4];
    const float* b1   = (const float*)d_in[5];
    const float* W2   = (const float*)d_in[6];
    const float* asw2 = (const float*)d_in[7];
    const float* adw2 = (const float*)d_in[8];
    const float* b2   = (const float*)d_in[9];
    const float* Wout = (const float*)d_in[10];
    const float* bout = (const float*)d_in[11];
    float* out = (float*)d_out;

    char* p = (char*)d_ws;
    auto carve = [&](size_t bytes) {
        void* r = (void*)p;
        p += (bytes + 255) & ~size_t(255);
        return r;
    };
    float*    o1       = (float*)   carve((size_t)N_NODES * 64 * 4);
    __half*   h2h      = (__half*)  carve((size_t)N_NODES * 32 * 2);
    float*    as1      = (float*)   carve((size_t)N_NODES * 2 * 4);
    float*    ad1      = (float*)   carve((size_t)N_NODES * 2 * 4);
    float*    as2      = (float*)   carve((size_t)N_NODES * 4);
    float*    ad2      = (float*)   carve((size_t)N_NODES * 4);
    int*      bh       = (int*)     carve((size_t)B_COARSE * NBIN * 4);
    int*      binoff   = (int*)     carve((size_t)(NBIN + 1) * 4);
    unsigned* ebin     = (unsigned*)carve((size_t)ETOT * 4);
    int*      rowstart = (int*)     carve((size_t)(N_NODES + 1) * 4);
    int*      csr_src  = (int*)     carve((size_t)ETOT * 4);

    const int TB = 256;

    // ---- fused node1 + coarse histogram; then scan, scatter, fine sort ----
    k_pre     <<<G_NODE1 + B_COARSE, TB, 0, stream>>>(x, W1, asw1, adw1, as1, ad1, ei, bh);
    k_cscan   <<<1, TB, 0, stream>>>(bh, binoff);
    k_cscatter<<<B_COARSE, TB, 0, stream>>>(ei, bh, binoff, ebin);
    k_fine    <<<NBIN, TB, 0, stream>>>(ebin, binoff, rowstart, csr_src);

    // ---- layer 1 ----
    k_gat1 <<<(N_NODES + 15) / 16, TB, 0, stream>>>(csr_src, rowstart, as1, ad1, x, W1, b1, o1);

    // ---- layer 2 ----
    k_node2<<<(N_NODES + 7) / 8, TB, 0, stream>>>(o1, W2, asw2, adw2, h2h, as2, ad2);
    k_gat2 <<<(N_NODES + 3) / 4, TB, 0, stream>>>(csr_src, rowstart, as2, ad2,
                                                  (const __half2*)h2h, b2, Wout, bout, out);
}